// Round 2
// baseline (3225.193 us; speedup 1.0000x reference)
//
#include <hip/hip_runtime.h>
#include <hip/hip_bf16.h>

#define NFEAT 256
#define HID 64
#define NCLASS 40
#define NUM_LAYERS 3

// ---------------------------------------------------------------------------
// lin1: h = relu(x @ w1.T + b1)   x:[N,256] w1:[64,256] -> h:[N,64]
// block = 256 thr = 4 waves; wave w owns k-chunk [64w,64w+64); lane = out j.
// Weights live in 64 VGPRs/lane; x staged in LDS, read as broadcast float4.
// ---------------------------------------------------------------------------
__global__ __launch_bounds__(256) void k_lin1(
    const float* __restrict__ x, const float* __restrict__ w1,
    const float* __restrict__ b1, float* __restrict__ h, int n_nodes)
{
    __shared__ float xs[8][NFEAT];     // 8 KB
    __shared__ float part[4][8][HID];  // 8 KB
    const int tid  = threadIdx.x;
    const int wave = tid >> 6;
    const int lane = tid & 63;

    float wreg[64];
#pragma unroll
    for (int k = 0; k < 64; k += 4) {
        float4 v = *reinterpret_cast<const float4*>(&w1[lane * NFEAT + wave * 64 + k]);
        wreg[k] = v.x; wreg[k + 1] = v.y; wreg[k + 2] = v.z; wreg[k + 3] = v.w;
    }

    const int nbatch = (n_nodes + 7) >> 3;
    for (int batch = blockIdx.x; batch < nbatch; batch += gridDim.x) {
        const int n0 = batch * 8;
        // stage 8 x-rows (512 float4, 2 per thread, coalesced)
        {
            const float4* xg = reinterpret_cast<const float4*>(x + (size_t)n0 * NFEAT);
            float4* xsv = reinterpret_cast<float4*>(&xs[0][0]);
#pragma unroll
            for (int i = 0; i < 2; ++i) {
                int idx  = tid + i * 256;
                int node = n0 + (idx >> 6);
                xsv[idx] = (node < n_nodes) ? xg[idx] : make_float4(0.f, 0.f, 0.f, 0.f);
            }
        }
        __syncthreads();
        for (int nl = 0; nl < 8; ++nl) {
            const float4* xrow = reinterpret_cast<const float4*>(&xs[nl][wave * 64]);
            float a0 = 0.f, a1 = 0.f, a2 = 0.f, a3 = 0.f;
#pragma unroll
            for (int kq = 0; kq < 16; ++kq) {
                float4 v = xrow[kq];
                a0 = fmaf(v.x, wreg[4 * kq + 0], a0);
                a1 = fmaf(v.y, wreg[4 * kq + 1], a1);
                a2 = fmaf(v.z, wreg[4 * kq + 2], a2);
                a3 = fmaf(v.w, wreg[4 * kq + 3], a3);
            }
            part[wave][nl][lane] = (a0 + a1) + (a2 + a3);
        }
        __syncthreads();
        // reduce 4 partials, add bias, relu, store (512 outputs / 256 thr)
#pragma unroll
        for (int i = 0; i < 2; ++i) {
            int o = tid + i * 256;
            int nl = o >> 6, j = o & 63;
            int node = n0 + nl;
            if (node < n_nodes) {
                float v = part[0][nl][j] + part[1][nl][j] + part[2][nl][j] + part[3][nl][j]
                          + b1[j];
                h[(size_t)node * HID + j] = fmaxf(v, 0.f);
            }
        }
        __syncthreads();
    }
}

// ---------------------------------------------------------------------------
// CSR build: histogram of dst, exclusive scan, fill col_src
// NOTE: harness passes integer inputs as int32 (edge_index: [2,E] int32).
// ---------------------------------------------------------------------------
__global__ void k_hist(const int* __restrict__ ei, int* __restrict__ cnt, int E)
{
    int i = blockIdx.x * blockDim.x + threadIdx.x;
    if (i < E) atomicAdd(&cnt[ei[E + i]], 1);
}

#define SCAN_C 2048
__global__ __launch_bounds__(512) void k_scan1(const int* __restrict__ cnt,
                                               int* __restrict__ btot, int n)
{
    __shared__ int sd[512];
    int b = blockIdx.x, t = threadIdx.x;
    int base = b * SCAN_C + t * 4;
    int s = 0;
#pragma unroll
    for (int i = 0; i < 4; ++i) { int idx = base + i; if (idx < n) s += cnt[idx]; }
    sd[t] = s; __syncthreads();
    for (int off = 256; off > 0; off >>= 1) {
        if (t < off) sd[t] += sd[t + off];
        __syncthreads();
    }
    if (t == 0) btot[b] = sd[0];
}

__global__ __launch_bounds__(1024) void k_scan2(int* __restrict__ btot, int nb)
{
    __shared__ int sd[1024];
    int t = threadIdx.x;
    int v = (t < nb) ? btot[t] : 0;
    sd[t] = v; __syncthreads();
    for (int off = 1; off < 1024; off <<= 1) {
        int x = sd[t];
        int add = (t >= off) ? sd[t - off] : 0;
        __syncthreads();
        sd[t] = x + add;
        __syncthreads();
    }
    if (t < nb) btot[t] = sd[t] - v;  // exclusive
}

__global__ __launch_bounds__(512) void k_scan3(const int* __restrict__ cnt,
                                               const int* __restrict__ btot,
                                               int* __restrict__ row_ptr,
                                               int* __restrict__ cursor, int n)
{
    __shared__ int sth[512];
    int b = blockIdx.x, t = threadIdx.x;
    int base = b * SCAN_C + t * 4;
    int v[4]; int s = 0;
#pragma unroll
    for (int i = 0; i < 4; ++i) { int idx = base + i; v[i] = (idx < n) ? cnt[idx] : 0; s += v[i]; }
    sth[t] = s; __syncthreads();
    int mine = s;
    for (int off = 1; off < 512; off <<= 1) {
        int x = sth[t];
        int add = (t >= off) ? sth[t - off] : 0;
        __syncthreads();
        sth[t] = x + add;
        __syncthreads();
    }
    int carry = btot[b] + (sth[t] - mine);
#pragma unroll
    for (int i = 0; i < 4; ++i) {
        int idx = base + i;
        if (idx < n) {
            row_ptr[idx] = carry;
            cursor[idx]  = carry;
            carry += v[i];
            if (idx == n - 1) row_ptr[n] = carry;  // = E
        }
    }
}

__global__ void k_fill(const int* __restrict__ ei, int* __restrict__ cursor,
                       int* __restrict__ col_src, int E)
{
    int i = blockIdx.x * blockDim.x + threadIdx.x;
    if (i < E) {
        int dst = ei[E + i];
        int p = atomicAdd(&cursor[dst], 1);
        col_src[p] = ei[i];
    }
}

// ---------------------------------------------------------------------------
// aggregation: ah[n] = sum_{e: dst=n} h[src[e]]   (wave per node, lane = feat)
// ---------------------------------------------------------------------------
__global__ __launch_bounds__(256) void k_agg(
    const float* __restrict__ h, const int* __restrict__ row_ptr,
    const int* __restrict__ col_src, float* __restrict__ ah, int n_nodes)
{
    int wid    = (blockIdx.x * blockDim.x + threadIdx.x) >> 6;
    int lane   = threadIdx.x & 63;
    int nwaves = (gridDim.x * blockDim.x) >> 6;
    for (int node = wid; node < n_nodes; node += nwaves) {
        int e0 = row_ptr[node], e1 = row_ptr[node + 1];
        float acc = 0.f;
        int e = e0;
        for (; e + 4 <= e1; e += 4) {
            int s0 = col_src[e], s1 = col_src[e + 1], s2 = col_src[e + 2], s3 = col_src[e + 3];
            float v0 = h[(size_t)s0 * HID + lane];
            float v1 = h[(size_t)s1 * HID + lane];
            float v2 = h[(size_t)s2 * HID + lane];
            float v3 = h[(size_t)s3 * HID + lane];
            acc += (v0 + v1) + (v2 + v3);
        }
        for (; e < e1; ++e) acc += h[(size_t)col_src[e] * HID + lane];
        ah[(size_t)node * HID + lane] = acc;
    }
}

// ---------------------------------------------------------------------------
// Wic[l][j][k] = sum_m w_ih[j][m] * gg_w[l][k][m]   (combined input matrix)
// (since agg = segsum(h) @ gg_w[l], gi = segsum(h) @ (gg_w[l] @ w_ih.T))
// ---------------------------------------------------------------------------
__global__ void k_wic(const float* __restrict__ gg_w, const float* __restrict__ w_ih,
                      float* __restrict__ Wic)
{
    int idx = blockIdx.x * blockDim.x + threadIdx.x;
    if (idx < NUM_LAYERS * 192 * 64) {
        int l = idx / (192 * 64);
        int j = (idx / 64) % 192;
        int k = idx % 64;
        const float* gw = gg_w + ((size_t)l * 64 + k) * 64;
        const float* wi = w_ih + (size_t)j * 64;
        float acc = 0.f;
#pragma unroll 4
        for (int m = 0; m < 64; ++m) acc = fmaf(wi[m], gw[m], acc);
        Wic[idx] = acc;
    }
}

// ---------------------------------------------------------------------------
// fused GRU: gi = ah@Wic.T + b_ih ; gh = h@w_hh.T + b_hh ; gates ; h updated
// 384 thr = 6 waves: waves 0-2 -> Wic chunks (read ah), 3-5 -> w_hh (read h).
// Each lane holds one 64-float weight row in VGPRs.
// ---------------------------------------------------------------------------
__global__ __launch_bounds__(384) void k_gru(
    const float* __restrict__ ah, float* __restrict__ h,
    const float* __restrict__ Wic, const float* __restrict__ whh,
    const float* __restrict__ b_ih, const float* __restrict__ b_hh, int n_nodes)
{
    __shared__ float g[8][384];  // 12 KB: per node [gi(192) | gh(192)]
    const int tid = threadIdx.x, wave = tid >> 6, lane = tid & 63;
    const int mat = wave / 3;    // 0: input path, 1: hidden path
    const int chunk = wave % 3;
    const int jg = chunk * 64 + lane;

    float wreg[64];
    {
        const float* wsrc = (mat == 0 ? Wic : whh) + (size_t)jg * 64;
#pragma unroll
        for (int k = 0; k < 64; k += 4) {
            float4 v = *reinterpret_cast<const float4*>(&wsrc[k]);
            wreg[k] = v.x; wreg[k + 1] = v.y; wreg[k + 2] = v.z; wreg[k + 3] = v.w;
        }
    }
    const float* srcbuf = (mat == 0) ? ah : h;
    const int slot = mat * 192 + chunk * 64 + lane;

    const int nbatch = (n_nodes + 7) >> 3;
    for (int batch = blockIdx.x; batch < nbatch; batch += gridDim.x) {
        const int n0 = batch * 8;
        for (int nl = 0; nl < 8; ++nl) {
            int node = n0 + nl;
            if (node < n_nodes) {
                const float4* r4 = reinterpret_cast<const float4*>(srcbuf + (size_t)node * HID);
                float a0 = 0.f, a1 = 0.f, a2 = 0.f, a3 = 0.f;
#pragma unroll
                for (int kq = 0; kq < 16; ++kq) {
                    float4 v = r4[kq];
                    a0 = fmaf(v.x, wreg[4 * kq + 0], a0);
                    a1 = fmaf(v.y, wreg[4 * kq + 1], a1);
                    a2 = fmaf(v.z, wreg[4 * kq + 2], a2);
                    a3 = fmaf(v.w, wreg[4 * kq + 3], a3);
                }
                g[nl][slot] = (a0 + a1) + (a2 + a3);
            }
        }
        __syncthreads();
        for (int o = tid; o < 512; o += 384) {
            int nl = o >> 6, j = o & 63;
            int node = n0 + nl;
            if (node < n_nodes) {
                float ir = g[nl][j]       + b_ih[j];
                float iz = g[nl][64 + j]  + b_ih[64 + j];
                float in_ = g[nl][128 + j] + b_ih[128 + j];
                float hr = g[nl][192 + j] + b_hh[j];
                float hz = g[nl][256 + j] + b_hh[64 + j];
                float hn = g[nl][320 + j] + b_hh[128 + j];
                float r = 1.f / (1.f + __expf(-(ir + hr)));
                float z = 1.f / (1.f + __expf(-(iz + hz)));
                float x2 = in_ + r * hn;
                float nn = 1.f - 2.f / (__expf(2.f * x2) + 1.f);  // tanh, inf-safe
                size_t hi = (size_t)node * HID + j;
                float hold = h[hi];
                h[hi] = (1.f - z) * nn + z * hold;
            }
        }
        __syncthreads();
    }
}

// ---------------------------------------------------------------------------
// out = softmax(h @ w2.T + b2)  wave per node; lane<40 = class; w2 in VGPRs
// ---------------------------------------------------------------------------
__global__ __launch_bounds__(256) void k_out(
    const float* __restrict__ h, const float* __restrict__ w2,
    const float* __restrict__ b2, float* __restrict__ out, int n_nodes)
{
    const int tid = threadIdx.x, lane = tid & 63;
    float wreg[64];
    float bias = 0.f;
    if (lane < NCLASS) {
#pragma unroll
        for (int k = 0; k < 64; k += 4) {
            float4 v = *reinterpret_cast<const float4*>(&w2[lane * HID + k]);
            wreg[k] = v.x; wreg[k + 1] = v.y; wreg[k + 2] = v.z; wreg[k + 3] = v.w;
        }
        bias = b2[lane];
    } else {
#pragma unroll
        for (int k = 0; k < 64; ++k) wreg[k] = 0.f;
    }
    int wid    = (blockIdx.x * blockDim.x + tid) >> 6;
    int nwaves = (gridDim.x * blockDim.x) >> 6;
    for (int node = wid; node < n_nodes; node += nwaves) {
        const float4* r4 = reinterpret_cast<const float4*>(h + (size_t)node * HID);
        float a0 = bias, a1 = 0.f, a2 = 0.f, a3 = 0.f;
#pragma unroll
        for (int kq = 0; kq < 16; ++kq) {
            float4 v = r4[kq];
            a0 = fmaf(v.x, wreg[4 * kq + 0], a0);
            a1 = fmaf(v.y, wreg[4 * kq + 1], a1);
            a2 = fmaf(v.z, wreg[4 * kq + 2], a2);
            a3 = fmaf(v.w, wreg[4 * kq + 3], a3);
        }
        float lg = (lane < NCLASS) ? (a0 + a1) + (a2 + a3) : -INFINITY;
        float m = lg;
#pragma unroll
        for (int off = 32; off > 0; off >>= 1) m = fmaxf(m, __shfl_xor(m, off, 64));
        float p = (lane < NCLASS) ? __expf(lg - m) : 0.f;
        float s = p;
#pragma unroll
        for (int off = 32; off > 0; off >>= 1) s += __shfl_xor(s, off, 64);
        if (lane < NCLASS) out[(size_t)node * NCLASS + lane] = p / s;
    }
}

// ---------------------------------------------------------------------------
extern "C" void kernel_launch(void* const* d_in, const int* in_sizes, int n_in,
                              void* d_out, int out_size, void* d_ws, size_t ws_size,
                              hipStream_t stream)
{
    const float* x    = (const float*)d_in[0];
    const int*   ei   = (const int*)d_in[1];    // int32 per harness contract
    const float* w1   = (const float*)d_in[2];
    const float* b1   = (const float*)d_in[3];
    const float* gg_w = (const float*)d_in[4];
    const float* w_ih = (const float*)d_in[5];
    const float* w_hh = (const float*)d_in[6];
    const float* b_ih = (const float*)d_in[7];
    const float* b_hh = (const float*)d_in[8];
    const float* w2   = (const float*)d_in[9];
    const float* b2   = (const float*)d_in[10];
    float*       out  = (float*)d_out;

    const int n = in_sizes[0] / NFEAT;   // 200000
    const int E = in_sizes[1] / 2;       // 1200000

    // workspace carve (~109 MB)
    char* ws = (char*)d_ws;
    float* h       = (float*)ws;  ws += (size_t)n * HID * 4;
    float* ah      = (float*)ws;  ws += (size_t)n * HID * 4;
    float* Wic     = (float*)ws;  ws += (size_t)NUM_LAYERS * 192 * 64 * 4;
    int*   row_ptr = (int*)ws;    ws += (size_t)(n + 1) * 4;
    int*   col_src = (int*)ws;    ws += (size_t)E * 4;
    int*   cnt     = (int*)ws;    ws += (size_t)n * 4;
    int*   cursor  = (int*)ws;    ws += (size_t)n * 4;
    int*   btot    = (int*)ws;    ws += 8192;

    const int nb = (n + SCAN_C - 1) / SCAN_C;

    hipMemsetAsync(cnt, 0, (size_t)n * 4, stream);
    k_wic<<<(NUM_LAYERS * 192 * 64 + 255) / 256, 256, 0, stream>>>(gg_w, w_ih, Wic);
    k_lin1<<<2048, 256, 0, stream>>>(x, w1, b1, h, n);
    k_hist<<<(E + 255) / 256, 256, 0, stream>>>(ei, cnt, E);
    k_scan1<<<nb, 512, 0, stream>>>(cnt, btot, n);
    k_scan2<<<1, 1024, 0, stream>>>(btot, nb);
    k_scan3<<<nb, 512, 0, stream>>>(cnt, btot, row_ptr, cursor, n);
    k_fill<<<(E + 255) / 256, 256, 0, stream>>>(ei, cursor, col_src, E);

    for (int l = 0; l < NUM_LAYERS; ++l) {
        k_agg<<<2048, 256, 0, stream>>>(h, row_ptr, col_src, ah, n);
        k_gru<<<1024, 384, 0, stream>>>(ah, h, Wic + (size_t)l * 192 * 64,
                                        w_hh, b_ih, b_hh, n);
    }
    k_out<<<2048, 256, 0, stream>>>(h, w2, b2, out, n);
}

// Round 3
// 1859.434 us; speedup vs baseline: 1.7345x; 1.7345x over previous
//
#include <hip/hip_runtime.h>
#include <hip/hip_bf16.h>

#define NFEAT 256
#define HID 64
#define NCLASS 40
#define NUM_LAYERS 3

// ---------------------------------------------------------------------------
// lin1: h = relu(x @ w1.T + b1)   x:[N,256] w1:[64,256] -> h:[N,64]
// ---------------------------------------------------------------------------
__global__ __launch_bounds__(256) void k_lin1(
    const float* __restrict__ x, const float* __restrict__ w1,
    const float* __restrict__ b1, float* __restrict__ h, int n_nodes)
{
    __shared__ float xs[8][NFEAT];     // 8 KB
    __shared__ float part[4][8][HID];  // 8 KB
    const int tid  = threadIdx.x;
    const int wave = tid >> 6;
    const int lane = tid & 63;

    float wreg[64];
#pragma unroll
    for (int k = 0; k < 64; k += 4) {
        float4 v = *reinterpret_cast<const float4*>(&w1[lane * NFEAT + wave * 64 + k]);
        wreg[k] = v.x; wreg[k + 1] = v.y; wreg[k + 2] = v.z; wreg[k + 3] = v.w;
    }

    const int nbatch = (n_nodes + 7) >> 3;
    for (int batch = blockIdx.x; batch < nbatch; batch += gridDim.x) {
        const int n0 = batch * 8;
        {
            const float4* xg = reinterpret_cast<const float4*>(x + (size_t)n0 * NFEAT);
            float4* xsv = reinterpret_cast<float4*>(&xs[0][0]);
#pragma unroll
            for (int i = 0; i < 2; ++i) {
                int idx  = tid + i * 256;
                int node = n0 + (idx >> 6);
                xsv[idx] = (node < n_nodes) ? xg[idx] : make_float4(0.f, 0.f, 0.f, 0.f);
            }
        }
        __syncthreads();
        for (int nl = 0; nl < 8; ++nl) {
            const float4* xrow = reinterpret_cast<const float4*>(&xs[nl][wave * 64]);
            float a0 = 0.f, a1 = 0.f, a2 = 0.f, a3 = 0.f;
#pragma unroll
            for (int kq = 0; kq < 16; ++kq) {
                float4 v = xrow[kq];
                a0 = fmaf(v.x, wreg[4 * kq + 0], a0);
                a1 = fmaf(v.y, wreg[4 * kq + 1], a1);
                a2 = fmaf(v.z, wreg[4 * kq + 2], a2);
                a3 = fmaf(v.w, wreg[4 * kq + 3], a3);
            }
            part[wave][nl][lane] = (a0 + a1) + (a2 + a3);
        }
        __syncthreads();
#pragma unroll
        for (int i = 0; i < 2; ++i) {
            int o = tid + i * 256;
            int nl = o >> 6, j = o & 63;
            int node = n0 + nl;
            if (node < n_nodes) {
                float v = part[0][nl][j] + part[1][nl][j] + part[2][nl][j] + part[3][nl][j]
                          + b1[j];
                h[(size_t)node * HID + j] = fmaxf(v, 0.f);
            }
        }
        __syncthreads();
    }
}

// ---------------------------------------------------------------------------
// CSR build: histogram of dst, exclusive scan, fill col_src  (int32 inputs)
// ---------------------------------------------------------------------------
__global__ void k_hist(const int* __restrict__ ei, int* __restrict__ cnt, int E)
{
    int i = blockIdx.x * blockDim.x + threadIdx.x;
    if (i < E) atomicAdd(&cnt[ei[E + i]], 1);
}

#define SCAN_C 2048
__global__ __launch_bounds__(512) void k_scan1(const int* __restrict__ cnt,
                                               int* __restrict__ btot, int n)
{
    __shared__ int sd[512];
    int b = blockIdx.x, t = threadIdx.x;
    int base = b * SCAN_C + t * 4;
    int s = 0;
#pragma unroll
    for (int i = 0; i < 4; ++i) { int idx = base + i; if (idx < n) s += cnt[idx]; }
    sd[t] = s; __syncthreads();
    for (int off = 256; off > 0; off >>= 1) {
        if (t < off) sd[t] += sd[t + off];
        __syncthreads();
    }
    if (t == 0) btot[b] = sd[0];
}

__global__ __launch_bounds__(1024) void k_scan2(int* __restrict__ btot, int nb)
{
    __shared__ int sd[1024];
    int t = threadIdx.x;
    int v = (t < nb) ? btot[t] : 0;
    sd[t] = v; __syncthreads();
    for (int off = 1; off < 1024; off <<= 1) {
        int x = sd[t];
        int add = (t >= off) ? sd[t - off] : 0;
        __syncthreads();
        sd[t] = x + add;
        __syncthreads();
    }
    if (t < nb) btot[t] = sd[t] - v;  // exclusive
}

__global__ __launch_bounds__(512) void k_scan3(const int* __restrict__ cnt,
                                               const int* __restrict__ btot,
                                               int* __restrict__ row_ptr,
                                               int* __restrict__ cursor, int n)
{
    __shared__ int sth[512];
    int b = blockIdx.x, t = threadIdx.x;
    int base = b * SCAN_C + t * 4;
    int v[4]; int s = 0;
#pragma unroll
    for (int i = 0; i < 4; ++i) { int idx = base + i; v[i] = (idx < n) ? cnt[idx] : 0; s += v[i]; }
    sth[t] = s; __syncthreads();
    int mine = s;
    for (int off = 1; off < 512; off <<= 1) {
        int x = sth[t];
        int add = (t >= off) ? sth[t - off] : 0;
        __syncthreads();
        sth[t] = x + add;
        __syncthreads();
    }
    int carry = btot[b] + (sth[t] - mine);
#pragma unroll
    for (int i = 0; i < 4; ++i) {
        int idx = base + i;
        if (idx < n) {
            row_ptr[idx] = carry;
            cursor[idx]  = carry;
            carry += v[i];
            if (idx == n - 1) row_ptr[n] = carry;  // = E
        }
    }
}

__global__ void k_fill(const int* __restrict__ ei, int* __restrict__ cursor,
                       int* __restrict__ col_src, int E)
{
    int i = blockIdx.x * blockDim.x + threadIdx.x;
    if (i < E) {
        int dst = ei[E + i];
        int p = atomicAdd(&cursor[dst], 1);
        col_src[p] = ei[i];
    }
}

// ---------------------------------------------------------------------------
// aggregation: ah[n] = sum_{e: dst=n} h[src[e]]   (wave per node, lane = feat)
// ---------------------------------------------------------------------------
__global__ __launch_bounds__(256) void k_agg(
    const float* __restrict__ h, const int* __restrict__ row_ptr,
    const int* __restrict__ col_src, float* __restrict__ ah, int n_nodes)
{
    int wid    = (blockIdx.x * blockDim.x + threadIdx.x) >> 6;
    int lane   = threadIdx.x & 63;
    int nwaves = (gridDim.x * blockDim.x) >> 6;
    for (int node = wid; node < n_nodes; node += nwaves) {
        int e0 = row_ptr[node], e1 = row_ptr[node + 1];
        float acc = 0.f;
        int e = e0;
        for (; e + 4 <= e1; e += 4) {
            int s0 = col_src[e], s1 = col_src[e + 1], s2 = col_src[e + 2], s3 = col_src[e + 3];
            float v0 = h[(size_t)s0 * HID + lane];
            float v1 = h[(size_t)s1 * HID + lane];
            float v2 = h[(size_t)s2 * HID + lane];
            float v3 = h[(size_t)s3 * HID + lane];
            acc += (v0 + v1) + (v2 + v3);
        }
        for (; e < e1; ++e) acc += h[(size_t)col_src[e] * HID + lane];
        ah[(size_t)node * HID + lane] = acc;
    }
}

// ---------------------------------------------------------------------------
// Wic[l][j][k] = sum_m w_ih[j][m] * gg_w[l][k][m]
// (agg = segsum(h) @ gg_w[l]  =>  gi = segsum(h) @ (gg_w[l] @ w_ih.T))
// ---------------------------------------------------------------------------
__global__ void k_wic(const float* __restrict__ gg_w, const float* __restrict__ w_ih,
                      float* __restrict__ Wic)
{
    int idx = blockIdx.x * blockDim.x + threadIdx.x;
    if (idx < NUM_LAYERS * 192 * 64) {
        int l = idx / (192 * 64);
        int j = (idx / 64) % 192;
        int k = idx % 64;
        const float* gw = gg_w + ((size_t)l * 64 + k) * 64;
        const float* wi = w_ih + (size_t)j * 64;
        float acc = 0.f;
#pragma unroll 4
        for (int m = 0; m < 64; ++m) acc = fmaf(wi[m], gw[m], acc);
        Wic[idx] = acc;
    }
}

// ---------------------------------------------------------------------------
// fused GRU v2: lane = node. Each thread holds its node's ah row (64 VGPR)
// and h row (64 VGPR); weights (Wic 192x64 + whh 192x64 fp32 = 96 KB) staged
// in LDS once per block, read wave-uniform (broadcast, conflict-free).
// j-loop: 6 dot products (384 FMA) per output j, then gate math, scattered
// dword store (L2 write-back merges; row = 2 lines written fully).
// No barriers in main loop. 512 thr = 8 waves; VGPR ~150 -> 2 waves/SIMD.
// ---------------------------------------------------------------------------
#define GRU_BLK 512
__global__ __launch_bounds__(GRU_BLK, 2) void k_gru2(
    const float* __restrict__ ah, float* __restrict__ h,
    const float* __restrict__ Wic, const float* __restrict__ whh,
    const float* __restrict__ b_ih, const float* __restrict__ b_hh, int n_nodes)
{
    __shared__ float wi[192 * 64];  // 48 KB
    __shared__ float wh[192 * 64];  // 48 KB
    const int tid = threadIdx.x;

    // cooperative weight staging: 3072 float4 each
    {
        const float4* s1 = reinterpret_cast<const float4*>(Wic);
        const float4* s2 = reinterpret_cast<const float4*>(whh);
        float4* d1 = reinterpret_cast<float4*>(wi);
        float4* d2 = reinterpret_cast<float4*>(wh);
        for (int i = tid; i < 3072; i += GRU_BLK) { d1[i] = s1[i]; d2[i] = s2[i]; }
    }
    __syncthreads();

    const int ngrp = (n_nodes + GRU_BLK - 1) / GRU_BLK;
    for (int grp = blockIdx.x; grp < ngrp; grp += gridDim.x) {
        const int node = grp * GRU_BLK + tid;
        const bool act = node < n_nodes;

        float ar[64], hr[64];
        if (act) {
            const float4* arow = reinterpret_cast<const float4*>(ah + (size_t)node * HID);
            const float4* hrow = reinterpret_cast<const float4*>(h + (size_t)node * HID);
#pragma unroll
            for (int kq = 0; kq < 16; ++kq) {
                float4 va = arow[kq];
                ar[4 * kq] = va.x; ar[4 * kq + 1] = va.y; ar[4 * kq + 2] = va.z; ar[4 * kq + 3] = va.w;
                float4 vh = hrow[kq];
                hr[4 * kq] = vh.x; hr[4 * kq + 1] = vh.y; hr[4 * kq + 2] = vh.z; hr[4 * kq + 3] = vh.w;
            }
        } else {
#pragma unroll
            for (int k = 0; k < 64; ++k) { ar[k] = 0.f; hr[k] = 0.f; }
        }

        for (int j = 0; j < 64; ++j) {
            const float4* wri = reinterpret_cast<const float4*>(&wi[(size_t)j * 64]);
            const float4* wzi = reinterpret_cast<const float4*>(&wi[(size_t)(64 + j) * 64]);
            const float4* wni = reinterpret_cast<const float4*>(&wi[(size_t)(128 + j) * 64]);
            const float4* wrh = reinterpret_cast<const float4*>(&wh[(size_t)j * 64]);
            const float4* wzh = reinterpret_cast<const float4*>(&wh[(size_t)(64 + j) * 64]);
            const float4* wnh = reinterpret_cast<const float4*>(&wh[(size_t)(128 + j) * 64]);
            float air = 0.f, aiz = 0.f, ain = 0.f;
            float bhr = 0.f, bhz = 0.f, bhn = 0.f;
#pragma unroll
            for (int kq = 0; kq < 16; ++kq) {
                float4 w0 = wri[kq], w1 = wzi[kq], w2 = wni[kq];
                float4 w3 = wrh[kq], w4 = wzh[kq], w5 = wnh[kq];
                float a0 = ar[4 * kq], a1 = ar[4 * kq + 1], a2 = ar[4 * kq + 2], a3 = ar[4 * kq + 3];
                float h0 = hr[4 * kq], h1 = hr[4 * kq + 1], h2 = hr[4 * kq + 2], h3 = hr[4 * kq + 3];
                air = fmaf(a0, w0.x, air); air = fmaf(a1, w0.y, air);
                air = fmaf(a2, w0.z, air); air = fmaf(a3, w0.w, air);
                aiz = fmaf(a0, w1.x, aiz); aiz = fmaf(a1, w1.y, aiz);
                aiz = fmaf(a2, w1.z, aiz); aiz = fmaf(a3, w1.w, aiz);
                ain = fmaf(a0, w2.x, ain); ain = fmaf(a1, w2.y, ain);
                ain = fmaf(a2, w2.z, ain); ain = fmaf(a3, w2.w, ain);
                bhr = fmaf(h0, w3.x, bhr); bhr = fmaf(h1, w3.y, bhr);
                bhr = fmaf(h2, w3.z, bhr); bhr = fmaf(h3, w3.w, bhr);
                bhz = fmaf(h0, w4.x, bhz); bhz = fmaf(h1, w4.y, bhz);
                bhz = fmaf(h2, w4.z, bhz); bhz = fmaf(h3, w4.w, bhz);
                bhn = fmaf(h0, w5.x, bhn); bhn = fmaf(h1, w5.y, bhn);
                bhn = fmaf(h2, w5.z, bhn); bhn = fmaf(h3, w5.w, bhn);
            }
            float ir  = air + b_ih[j];
            float iz  = aiz + b_ih[64 + j];
            float in_ = ain + b_ih[128 + j];
            float hrv = bhr + b_hh[j];
            float hzv = bhz + b_hh[64 + j];
            float hnv = bhn + b_hh[128 + j];
            float r = 1.f / (1.f + __expf(-(ir + hrv)));
            float z = 1.f / (1.f + __expf(-(iz + hzv)));
            float x2 = in_ + r * hnv;
            float nn = 1.f - 2.f / (__expf(2.f * x2) + 1.f);  // tanh, inf-safe
            if (act) {
                size_t hi = (size_t)node * HID + j;
                float hold = h[hi];
                h[hi] = (1.f - z) * nn + z * hold;
            }
        }
    }
}

// ---------------------------------------------------------------------------
// out = softmax(h @ w2.T + b2)  wave per node; lane<40 = class; w2 in VGPRs
// ---------------------------------------------------------------------------
__global__ __launch_bounds__(256) void k_out(
    const float* __restrict__ h, const float* __restrict__ w2,
    const float* __restrict__ b2, float* __restrict__ out, int n_nodes)
{
    const int tid = threadIdx.x, lane = tid & 63;
    float wreg[64];
    float bias = 0.f;
    if (lane < NCLASS) {
#pragma unroll
        for (int k = 0; k < 64; k += 4) {
            float4 v = *reinterpret_cast<const float4*>(&w2[lane * HID + k]);
            wreg[k] = v.x; wreg[k + 1] = v.y; wreg[k + 2] = v.z; wreg[k + 3] = v.w;
        }
        bias = b2[lane];
    } else {
#pragma unroll
        for (int k = 0; k < 64; ++k) wreg[k] = 0.f;
    }
    int wid    = (blockIdx.x * blockDim.x + tid) >> 6;
    int nwaves = (gridDim.x * blockDim.x) >> 6;
    for (int node = wid; node < n_nodes; node += nwaves) {
        const float4* r4 = reinterpret_cast<const float4*>(h + (size_t)node * HID);
        float a0 = bias, a1 = 0.f, a2 = 0.f, a3 = 0.f;
#pragma unroll
        for (int kq = 0; kq < 16; ++kq) {
            float4 v = r4[kq];
            a0 = fmaf(v.x, wreg[4 * kq + 0], a0);
            a1 = fmaf(v.y, wreg[4 * kq + 1], a1);
            a2 = fmaf(v.z, wreg[4 * kq + 2], a2);
            a3 = fmaf(v.w, wreg[4 * kq + 3], a3);
        }
        float lg = (lane < NCLASS) ? (a0 + a1) + (a2 + a3) : -INFINITY;
        float m = lg;
#pragma unroll
        for (int off = 32; off > 0; off >>= 1) m = fmaxf(m, __shfl_xor(m, off, 64));
        float p = (lane < NCLASS) ? __expf(lg - m) : 0.f;
        float s = p;
#pragma unroll
        for (int off = 32; off > 0; off >>= 1) s += __shfl_xor(s, off, 64);
        if (lane < NCLASS) out[(size_t)node * NCLASS + lane] = p / s;
    }
}

// ---------------------------------------------------------------------------
extern "C" void kernel_launch(void* const* d_in, const int* in_sizes, int n_in,
                              void* d_out, int out_size, void* d_ws, size_t ws_size,
                              hipStream_t stream)
{
    const float* x    = (const float*)d_in[0];
    const int*   ei   = (const int*)d_in[1];    // int32 per harness contract
    const float* w1   = (const float*)d_in[2];
    const float* b1   = (const float*)d_in[3];
    const float* gg_w = (const float*)d_in[4];
    const float* w_ih = (const float*)d_in[5];
    const float* w_hh = (const float*)d_in[6];
    const float* b_ih = (const float*)d_in[7];
    const float* b_hh = (const float*)d_in[8];
    const float* w2   = (const float*)d_in[9];
    const float* b2   = (const float*)d_in[10];
    float*       out  = (float*)d_out;

    const int n = in_sizes[0] / NFEAT;   // 200000
    const int E = in_sizes[1] / 2;       // 1200000

    // workspace carve (~109 MB)
    char* ws = (char*)d_ws;
    float* h       = (float*)ws;  ws += (size_t)n * HID * 4;
    float* ah      = (float*)ws;  ws += (size_t)n * HID * 4;
    float* Wic     = (float*)ws;  ws += (size_t)NUM_LAYERS * 192 * 64 * 4;
    int*   row_ptr = (int*)ws;    ws += (size_t)(n + 1) * 4;
    int*   col_src = (int*)ws;    ws += (size_t)E * 4;
    int*   cnt     = (int*)ws;    ws += (size_t)n * 4;
    int*   cursor  = (int*)ws;    ws += (size_t)n * 4;
    int*   btot    = (int*)ws;    ws += 8192;

    const int nb = (n + SCAN_C - 1) / SCAN_C;

    hipMemsetAsync(cnt, 0, (size_t)n * 4, stream);
    k_wic<<<(NUM_LAYERS * 192 * 64 + 255) / 256, 256, 0, stream>>>(gg_w, w_ih, Wic);
    k_lin1<<<2048, 256, 0, stream>>>(x, w1, b1, h, n);
    k_hist<<<(E + 255) / 256, 256, 0, stream>>>(ei, cnt, E);
    k_scan1<<<nb, 512, 0, stream>>>(cnt, btot, n);
    k_scan2<<<1, 1024, 0, stream>>>(btot, nb);
    k_scan3<<<nb, 512, 0, stream>>>(cnt, btot, row_ptr, cursor, n);
    k_fill<<<(E + 255) / 256, 256, 0, stream>>>(ei, cursor, col_src, E);

    const int ngrp = (n + GRU_BLK - 1) / GRU_BLK;  // 391
    for (int l = 0; l < NUM_LAYERS; ++l) {
        k_agg<<<2048, 256, 0, stream>>>(h, row_ptr, col_src, ah, n);
        k_gru2<<<ngrp, GRU_BLK, 0, stream>>>(ah, h, Wic + (size_t)l * 192 * 64,
                                             w_hh, b_ih, b_hh, n);
    }
    k_out<<<2048, 256, 0, stream>>>(h, w2, b2, out, n);
}